// Round 5
// baseline (24.307 us; speedup 1.0000x reference)
//
#include <hip/hip_runtime.h>

// MultiScaleHead: B=16, L=2048, H=1024, P=16, S=128
#define B_ 16
#define L_ 2048
#define H_ 1024
#define P_ 16
#define S_ 128

// Single fused kernel, one block per batch, 1024 threads (16 waves).
// out[b,j] = sum_s w[b,s] * dot(backbone[b, sent_head[b,s], :], W[j,:]) + bias[j]
// All 32 row-loads per thread issued up-front (fully unrolled, registers);
// the weights computation overlaps the load stream; FMA phase is pure VALU.
__global__ void __launch_bounds__(1024) msh_fused(
        const float* __restrict__ backbone,
        const int* __restrict__ par_head,
        const int* __restrict__ par_tail,
        const int* __restrict__ sent_head,
        const float* __restrict__ W,
        const float* __restrict__ bias,
        float* __restrict__ out) {
    int b = blockIdx.x;
    int t = threadIdx.x;
    int wave = t >> 6, lane = t & 63;
    int grp = t >> 8, q = t & 255;      // 4 sentence-groups x 256 H-slots

    __shared__ int   sh[S_];
    __shared__ int   ph[P_], pt[P_];
    __shared__ float inv_scnt[P_];
    __shared__ int   validp[P_];
    __shared__ float wgt[S_];
    __shared__ float red[16][5];

    if (t < S_) sh[t] = sent_head[b * S_ + t];
    if (t < P_) { ph[t] = par_head[b * P_ + t]; pt[t] = par_tail[b * P_ + t]; }
    __syncthreads();

    // ---- Issue ALL long-latency loads up-front (depend only on sh) ----
    const float4* bb4 = reinterpret_cast<const float4*>(
        backbone + (size_t)b * L_ * H_);
    float4 v[32];
#pragma unroll
    for (int i = 0; i < 32; ++i)
        v[i] = bb4[(size_t)sh[grp + 4 * i] * (H_ / 4) + q];

    const float4* W4 = reinterpret_cast<const float4*>(W);
    float4 wj[5];
#pragma unroll
    for (int j = 0; j < 5; ++j)
        wj[j] = W4[j * (H_ / 4) + q];

    // ---- Weights: wave p handles paragraph p (16 waves, 16 paragraphs),
    //      overlapped with the outstanding global loads ----
    {
        int p  = wave;
        int h0 = ph[p], t0 = pt[p];
        int s1 = lane, s2 = lane + 64;
        int in1 = (h0 <= sh[s1]) && (sh[s1] <= t0);
        int in2 = (h0 <= sh[s2]) && (sh[s2] <= t0);
        int cnt = in1 + in2;
        int nz  = (in1 && sh[s1] != 0) || (in2 && sh[s2] != 0);
        for (int off = 32; off > 0; off >>= 1) {
            cnt += __shfl_down(cnt, off, 64);
            nz  |= __shfl_down(nz,  off, 64);
        }
        if (lane == 0) {
            int valid = ((t0 - h0) > 2) && nz;
            validp[p] = valid;
            inv_scnt[p] = valid ? 1.0f / (float)(cnt > 1 ? cnt : 1) : 0.0f;
        }
    }
    __syncthreads();
    if (t < S_) {
        int myh = sh[t];
        float w = 0.0f; int pc = 0;
        for (int p = 0; p < P_; ++p) {
            pc += validp[p];
            if (ph[p] <= myh && myh <= pt[p]) w += inv_scnt[p];
        }
        wgt[t] = w / (float)(pc > 1 ? pc : 1);
    }
    __syncthreads();

    // ---- Weighted accumulate (pure VALU; loads already drained) ----
    float4 acc = make_float4(0.f, 0.f, 0.f, 0.f);
#pragma unroll
    for (int i = 0; i < 32; ++i) {
        float w = wgt[grp + 4 * i];
        acc.x += w * v[i].x; acc.y += w * v[i].y;
        acc.z += w * v[i].z; acc.w += w * v[i].w;
    }

    // ---- 5 dot products + block reduction ----
    float pj[5];
#pragma unroll
    for (int j = 0; j < 5; ++j)
        pj[j] = acc.x * wj[j].x + acc.y * wj[j].y
              + acc.z * wj[j].z + acc.w * wj[j].w;
#pragma unroll
    for (int j = 0; j < 5; ++j) {
        float vv = pj[j];
        for (int off = 32; off > 0; off >>= 1) vv += __shfl_down(vv, off, 64);
        pj[j] = vv;
    }
    if (lane == 0) {
#pragma unroll
        for (int j = 0; j < 5; ++j) red[wave][j] = pj[j];
    }
    __syncthreads();

    if (t < 5) {
        float tot = 0.0f;
#pragma unroll
        for (int i = 0; i < 16; ++i) tot += red[i][t];
        out[b * 5 + t] = tot + bias[t];
    }
}

extern "C" void kernel_launch(void* const* d_in, const int* in_sizes, int n_in,
                              void* d_out, int out_size, void* d_ws, size_t ws_size,
                              hipStream_t stream) {
    const float* backbone  = (const float*)d_in[0];
    // d_in[1] = attention_mask (unused by reference)
    const int*   par_head  = (const int*)d_in[2];
    const int*   par_tail  = (const int*)d_in[3];
    // d_in[4] = paragraph_attention_mask (unused)
    const int*   sent_head = (const int*)d_in[5];
    // d_in[6] = sentence_tail_idxs (unused), d_in[7] = sentence_attention_mask (unused)
    const float* W         = (const float*)d_in[8];
    const float* bias      = (const float*)d_in[9];

    float* out = (float*)d_out;

    msh_fused<<<B_, 1024, 0, stream>>>(backbone, par_head, par_tail, sent_head,
                                       W, bias, out);
}

// Round 6
// 12.585 us; speedup vs baseline: 1.9315x; 1.9315x over previous
//
#include <hip/hip_runtime.h>

// MultiScaleHead: B=16, L=2048, H=1024, P=16, S=128
#define B_ 16
#define L_ 2048
#define H_ 1024
#define P_ 16
#define S_ 128

// Single fused kernel, one block per batch, 512 threads (8 waves).
// 2 waves/SIMD -> 256-VGPR budget: float4 v[32] stays in registers (R5's
// spill at 1024 threads is avoided). Each thread: one H-slot (q), one of 2
// sentence groups (grp); 64 sentences/thread, 32 prefetched up-front
// (256 KB/CU in flight), second 32 software-pipelined behind the FMAs.
__global__ void __launch_bounds__(512) msh_fused(
        const float* __restrict__ backbone,
        const int* __restrict__ par_head,
        const int* __restrict__ par_tail,
        const int* __restrict__ sent_head,
        const float* __restrict__ W,
        const float* __restrict__ bias,
        float* __restrict__ out) {
    int b = blockIdx.x;
    int t = threadIdx.x;
    int wave = t >> 6, lane = t & 63;
    int grp = t >> 8, q = t & 255;      // 2 sentence-groups x 256 H-slots

    __shared__ int   sh[S_];
    __shared__ int   ph[P_], pt[P_];
    __shared__ float inv_scnt[P_];
    __shared__ int   validp[P_];
    __shared__ float wgt[S_];
    __shared__ float red[8][5];

    if (t < S_) sh[t] = sent_head[b * S_ + t];
    if (t < P_) { ph[t] = par_head[b * P_ + t]; pt[t] = par_tail[b * P_ + t]; }
    __syncthreads();

    // ---- Issue 32 row loads up-front (sentences s = 2*i + grp) ----
    const float4* bb4 = reinterpret_cast<const float4*>(
        backbone + (size_t)b * L_ * H_);
    float4 v[32];
#pragma unroll
    for (int i = 0; i < 32; ++i)
        v[i] = bb4[(size_t)sh[2 * i + grp] * (H_ / 4) + q];

    const float4* W4 = reinterpret_cast<const float4*>(W);
    float4 wj[5];
#pragma unroll
    for (int j = 0; j < 5; ++j)
        wj[j] = W4[j * (H_ / 4) + q];

    // ---- Weights (overlapped with loads): wave w -> paragraphs 2w, 2w+1 ----
#pragma unroll
    for (int k = 0; k < 2; ++k) {
        int p  = 2 * wave + k;
        int h0 = ph[p], t0 = pt[p];
        int s1 = lane, s2 = lane + 64;
        int in1 = (h0 <= sh[s1]) && (sh[s1] <= t0);
        int in2 = (h0 <= sh[s2]) && (sh[s2] <= t0);
        int cnt = in1 + in2;
        int nz  = (in1 && sh[s1] != 0) || (in2 && sh[s2] != 0);
        for (int off = 32; off > 0; off >>= 1) {
            cnt += __shfl_down(cnt, off, 64);
            nz  |= __shfl_down(nz,  off, 64);
        }
        if (lane == 0) {
            int valid = ((t0 - h0) > 2) && nz;
            validp[p] = valid;
            inv_scnt[p] = valid ? 1.0f / (float)(cnt > 1 ? cnt : 1) : 0.0f;
        }
    }
    __syncthreads();
    if (t < S_) {
        int myh = sh[t];
        float w = 0.0f; int pc = 0;
        for (int p = 0; p < P_; ++p) {
            pc += validp[p];
            if (ph[p] <= myh && myh <= pt[p]) w += inv_scnt[p];
        }
        wgt[t] = w / (float)(pc > 1 ? pc : 1);
    }
    __syncthreads();

    // ---- FMA half A, reloading each slot for half B as it frees ----
    float4 acc = make_float4(0.f, 0.f, 0.f, 0.f);
#define FMA4(wv, vv) do { float _w = (wv); \
        acc.x += _w * (vv).x; acc.y += _w * (vv).y; \
        acc.z += _w * (vv).z; acc.w += _w * (vv).w; } while (0)
#pragma unroll
    for (int i = 0; i < 32; ++i) {
        float w = wgt[2 * i + grp];
        float4 a = v[i];
        v[i] = bb4[(size_t)sh[64 + 2 * i + grp] * (H_ / 4) + q];  // half B
        FMA4(w, a);
    }
#pragma unroll
    for (int i = 0; i < 32; ++i)
        FMA4(wgt[64 + 2 * i + grp], v[i]);
#undef FMA4

    // ---- 5 dot products + block reduction (8 waves) ----
    float pj[5];
#pragma unroll
    for (int j = 0; j < 5; ++j)
        pj[j] = acc.x * wj[j].x + acc.y * wj[j].y
              + acc.z * wj[j].z + acc.w * wj[j].w;
#pragma unroll
    for (int j = 0; j < 5; ++j) {
        float vv = pj[j];
        for (int off = 32; off > 0; off >>= 1) vv += __shfl_down(vv, off, 64);
        pj[j] = vv;
    }
    if (lane == 0) {
#pragma unroll
        for (int j = 0; j < 5; ++j) red[wave][j] = pj[j];
    }
    __syncthreads();

    if (t < 5) {
        float tot = 0.0f;
#pragma unroll
        for (int i = 0; i < 8; ++i) tot += red[i][t];
        out[b * 5 + t] = tot + bias[t];
    }
}

extern "C" void kernel_launch(void* const* d_in, const int* in_sizes, int n_in,
                              void* d_out, int out_size, void* d_ws, size_t ws_size,
                              hipStream_t stream) {
    const float* backbone  = (const float*)d_in[0];
    // d_in[1] = attention_mask (unused by reference)
    const int*   par_head  = (const int*)d_in[2];
    const int*   par_tail  = (const int*)d_in[3];
    // d_in[4] = paragraph_attention_mask (unused)
    const int*   sent_head = (const int*)d_in[5];
    // d_in[6] = sentence_tail_idxs (unused), d_in[7] = sentence_attention_mask (unused)
    const float* W         = (const float*)d_in[8];
    const float* bias      = (const float*)d_in[9];

    float* out = (float*)d_out;

    msh_fused<<<B_, 512, 0, stream>>>(backbone, par_head, par_tail, sent_head,
                                      W, bias, out);
}